// Round 3
// baseline (150.629 us; speedup 1.0000x reference)
//
#include <hip/hip_runtime.h>
#include <hip/hip_bf16.h>
#include <math.h>

// Problem constants (from reference)
#define NDIM   8
#define NBINS  64
#define LOG_BETA   (-13.815510557964274f)  // log(1e-6)
#define LN2F       0.69314718055994531f
// mesh is geometric: boundary_j (original coords) = x1L*(1.2^j-1)/0.2, j=0..32
// bin index from |x|: g = log2(1 + ALPHA*|x|) / log2(1.2);  ALPHA = (1.2^32-1)/10
#define ALPHA      34.0821892f
#define INV_LOG2R  3.80178401692393f       // 1/log2(1.2)

__global__ __launch_bounds__(256, 8) void cdfq_fused(const float* __restrict__ x,
                                                     const float* __restrict__ logdet_in,
                                                     const float* __restrict__ p,
                                                     float* __restrict__ y_out,
                                                     float* __restrict__ ld_out,
                                                     int n)
{
    __shared__ float  mesh[65];
    __shared__ float  elmt[64];
    __shared__ float  sc[NDIM];
    __shared__ float  pdfs[NDIM][65];      // [d][k] — bank-friendly (65 stride)
    __shared__ float  cell[NDIM][64];
    __shared__ float4 stbl[NDIM * NBINS];  // [d][k]: {v1, slope, F_pre, mesh_k}

    const int t = threadIdx.x;

    // ---- prep phase (redundant per block; removes a serializing launch) ----
    if (t < 65) {
        float fidx = (float)t - 32.0f;
        float a = fabsf(fidx);
        float x1L = 2.0f / (powf(1.2f, 32.0f) - 1.0f);
        float xr = x1L * (powf(1.2f, a) - 1.0f) / 0.2f;
        xr = (fidx >= 0.0f) ? xr : -xr;
        xr = (xr + 10.0f) / 20.0f;
        if (t == 0)  xr = 0.0f;
        if (t == 64) xr = 1.0f;
        mesh[t] = xr;
    }
    for (int idx = t; idx < 63 * NDIM; idx += 256) {      // exp(p) -> pdfs[d][k+1]
        int d = idx & 7, k = idx >> 3;
        pdfs[d][k + 1] = expf(p[k * NDIM + d]);
    }
    if (t < NDIM) { pdfs[t][0] = 1e-6f; pdfs[t][64] = 1e-6f; }
    __syncthreads();
    if (t < 64) elmt[t] = mesh[t + 1] - mesh[t];
    __syncthreads();

    if (t < 64) {   // wave 0: per-dim normalization scale via shuffle reduce
        for (int d = 0; d < NDIM; ++d) {
            float w = 0.0f;
            if (t < 63) w = pdfs[d][t + 1] * 0.5f * (elmt[t] + elmt[t + 1]);
            for (int off = 32; off > 0; off >>= 1) w += __shfl_down(w, off);
            if (t == 0) sc[d] = (1.0f - (elmt[0] + elmt[63]) * 5e-7f) / w;
        }
    }
    __syncthreads();
    for (int idx = t; idx < 63 * NDIM; idx += 256) {      // apply scale
        int d = idx & 7, k = idx >> 3;
        pdfs[d][k + 1] *= sc[d];
    }
    __syncthreads();
    for (int idx = t; idx < NDIM * NBINS; idx += 256) {   // cell integrals
        int d = idx >> 6, k = idx & 63;
        cell[d][k] = 0.5f * (pdfs[d][k] + pdfs[d][k + 1]) * elmt[k];
    }
    __syncthreads();
    if (t < 64) {   // wave 0: exclusive scan per dim + pack table
        for (int d = 0; d < NDIM; ++d) {
            float c0 = cell[d][t];
            float v = c0;
            for (int off = 1; off < 64; off <<= 1) {
                float w = __shfl_up(v, off);
                if (t >= off) v += w;
            }
            float Fpre = v - c0;                 // exclusive prefix
            float v1 = pdfs[d][t];
            float v2 = pdfs[d][t + 1];
            stbl[d * 64 + t] = make_float4(v1, (v2 - v1) / elmt[t], Fpre, mesh[t]);
        }
    }
    __syncthreads();

    // ---- main phase: 4 interleaved items/thread, all loads issued up front ----
    const int T  = gridDim.x * blockDim.x;          // item stride (coalesced per load)
    const int i0 = blockIdx.x * blockDim.x + t;
    const float4* xv = (const float4*)x;

    int   ii[4];
    float4 A[4], B[4];
    float  L[4];
#pragma unroll
    for (int j = 0; j < 4; ++j) {
        int i = i0 + j * T;
        ii[j] = i;
        if (i < n) {                               // n==4T in practice; guard for safety
            A[j] = xv[2 * (size_t)i];
            B[j] = xv[2 * (size_t)i + 1];
            L[j] = logdet_in[i];
        }
    }

#pragma unroll
    for (int j = 0; j < 4; ++j) {
        int i = ii[j];
        if (i >= n) continue;
        float ld = L[j];
        float xd[8] = {A[j].x, A[j].y, A[j].z, A[j].w, B[j].x, B[j].y, B[j].z, B[j].w};
        float yd[8], dd[8];

#pragma unroll
        for (int d = 0; d < 8; ++d) {
            float xo = xd[d];
            float xs = fmaf(xo, 0.05f, 0.5f);            // (x+10)/20 to 1 ulp
            float u  = fabsf(xo);
            // analytic bin: g = log2(1 + alpha*u)/log2(1.2); one v_log_f32
            float g  = __log2f(fmaf(ALPHA, u, 1.0f)) * INV_LOG2R;
            int jp = (int)fminf(g, 31.0f);               // floor, x >= 0 side
            int jn = (int)ceilf(fminf(g, 32.0f));        // ceil,  x <  0 side
            int k  = (xo >= 0.0f) ? (32 + jp) : (32 - jn);

            float4 tb = stbl[(d << 6) + k];              // {v1, slope, F_pre, mesh_k}
            float xm  = xs - tb.w;
            bool cov  = (xs >= 0.0f) && (xs < 1.0f);

            float yc = tb.z + xm * fmaf(0.5f * xm, tb.y, tb.x);
            float dl = fmaf(xm, tb.y, tb.x);
            float yy = cov ? yc : xs;
            dd[d]    = cov ? dl : 1.0f;

            yy = fmaf(yy, 20.0f, -10.0f);
            if (yy > 10.0f)  { yy = fmaf(1e-6f, yy - 10.0f, 10.0f);  ld += LOG_BETA; }
            if (yy < -10.0f) { yy = fmaf(1e-6f, yy + 10.0f, -10.0f); ld += LOG_BETA; }
            yd[d] = yy;
        }

        // sum of logs as logs of pairwise products: 4 x v_log_f32
        // (pair product >= (1e-6)^2 = 1e-12 — no fp32 underflow)
        float l01 = __log2f(dd[0] * dd[1]);
        float l23 = __log2f(dd[2] * dd[3]);
        float l45 = __log2f(dd[4] * dd[5]);
        float l67 = __log2f(dd[6] * dd[7]);
        ld = fmaf((l01 + l23) + (l45 + l67), LN2F, ld);

        float4* yo = (float4*)y_out + 2 * (size_t)i;
        yo[0] = make_float4(yd[0], yd[1], yd[2], yd[3]);
        yo[1] = make_float4(yd[4], yd[5], yd[6], yd[7]);
        ld_out[i] = ld;
    }
}

extern "C" void kernel_launch(void* const* d_in, const int* in_sizes, int n_in,
                              void* d_out, int out_size, void* d_ws, size_t ws_size,
                              hipStream_t stream) {
    const float* x      = (const float*)d_in[0];   // [N, 8]
    const float* logdet = (const float*)d_in[1];   // [N, 1]
    const float* p      = (const float*)d_in[2];   // [63, 8]

    const int n = in_sizes[1];                     // N points
    float* y_out  = (float*)d_out;                 // [N*8]
    float* ld_out = (float*)d_out + (size_t)n * NDIM;  // [N]

    const int block = 256;
    const int grid  = (n + block * 4 - 1) / (block * 4);   // 4 items/thread, one pass
    cdfq_fused<<<grid, block, 0, stream>>>(x, logdet, p, y_out, ld_out, n);
}

// Round 4
// 139.623 us; speedup vs baseline: 1.0788x; 1.0788x over previous
//
#include <hip/hip_runtime.h>
#include <hip/hip_bf16.h>
#include <math.h>

// Problem constants (from reference)
#define NDIM   8
#define NBINS  64
#define LOG_BETA   (-13.815510557964274f)  // log(1e-6)
#define LN2F       0.69314718055994531f
// mesh is geometric: boundary_j (original coords) = x1L*(1.2^j-1)/0.2, j=0..32
// bin index from |x|: g = log2(1 + ALPHA*|x|) / log2(1.2);  ALPHA = (1.2^32-1)/10
#define ALPHA      34.0821892f
#define INV_LOG2R  3.80178401692393f       // 1/log2(1.2)

__global__ __launch_bounds__(256, 8) void cdfq_fused(const float* __restrict__ x,
                                                     const float* __restrict__ logdet_in,
                                                     const float* __restrict__ p,
                                                     float* __restrict__ y_out,
                                                     float* __restrict__ ld_out,
                                                     int n)
{
    __shared__ float  mesh[65];
    __shared__ float  elmt[64];
    __shared__ float  sc[NDIM];
    __shared__ float  pdfs[NDIM][65];      // [d][k] — bank-friendly (65 stride)
    __shared__ float4 stbl[NDIM * NBINS];  // [d][k]: {v1, slope, F_pre, mesh_k}

    const int t  = threadIdx.x;
    const int T  = gridDim.x * blockDim.x;         // item stride (coalesced per load)
    const int i0 = blockIdx.x * blockDim.x + t;
    const int iters = n / T;                       // uniform; n == 4T for this problem
    const float4* xv = (const float4*)x;

    // ---- prologue loads for iteration 0: issued BEFORE prep so the first
    //      memory latency hides behind prep's VALU/shuffle work ----
    float4 Ac, Bc; float Lc;
    if (iters > 0) {
        Ac = xv[2 * (size_t)i0];
        Bc = xv[2 * (size_t)i0 + 1];
        Lc = logdet_in[i0];
    }
    __builtin_amdgcn_sched_barrier(0);   // do not sink these below prep

    // ---- prep phase (redundant per block; removes a serializing launch) ----
    if (t < 65) {
        float fidx = (float)t - 32.0f;
        float a = fabsf(fidx);
        float x1L = 2.0f / (powf(1.2f, 32.0f) - 1.0f);
        float xr = x1L * (powf(1.2f, a) - 1.0f) / 0.2f;
        xr = (fidx >= 0.0f) ? xr : -xr;
        xr = (xr + 10.0f) / 20.0f;
        if (t == 0)  xr = 0.0f;
        if (t == 64) xr = 1.0f;
        mesh[t] = xr;
    }
    for (int idx = t; idx < 63 * NDIM; idx += 256) {      // exp(p) -> pdfs[d][k+1]
        int d = idx & 7, k = idx >> 3;
        pdfs[d][k + 1] = expf(p[k * NDIM + d]);
    }
    if (t < NDIM) { pdfs[t][0] = 1e-6f; pdfs[t][64] = 1e-6f; }
    __syncthreads();
    if (t < 64) elmt[t] = mesh[t + 1] - mesh[t];
    __syncthreads();

    if (t < 64) {   // wave 0: per-dim normalization scale via shuffle reduce
        for (int d = 0; d < NDIM; ++d) {
            float w = 0.0f;
            if (t < 63) w = pdfs[d][t + 1] * 0.5f * (elmt[t] + elmt[t + 1]);
            for (int off = 32; off > 0; off >>= 1) w += __shfl_down(w, off);
            if (t == 0) sc[d] = (1.0f - (elmt[0] + elmt[63]) * 5e-7f) / w;
        }
    }
    __syncthreads();
    for (int idx = t; idx < 63 * NDIM; idx += 256) {      // apply scale
        int d = idx & 7, k = idx >> 3;
        pdfs[d][k + 1] *= sc[d];
    }
    __syncthreads();
    if (t < 64) {   // wave 0: cell integral + exclusive scan per dim + pack table
        for (int d = 0; d < NDIM; ++d) {
            float c0 = 0.5f * (pdfs[d][t] + pdfs[d][t + 1]) * elmt[t];
            float v = c0;
            for (int off = 1; off < 64; off <<= 1) {
                float w = __shfl_up(v, off);
                if (t >= off) v += w;
            }
            float Fpre = v - c0;                 // exclusive prefix
            float v1 = pdfs[d][t];
            float v2 = pdfs[d][t + 1];
            stbl[d * 64 + t] = make_float4(v1, (v2 - v1) / elmt[t], Fpre, mesh[t]);
        }
    }
    __syncthreads();

    // ---- per-point body (shared by pipelined loop and remainder) ----
    auto body = [&](float4 A, float4 B, float Lin, int i) {
        float ld = Lin;
        float xd[8] = {A.x, A.y, A.z, A.w, B.x, B.y, B.z, B.w};
        float yd[8], dd[8];

#pragma unroll
        for (int d = 0; d < 8; ++d) {
            float xo = xd[d];
            float xs = fmaf(xo, 0.05f, 0.5f);            // (x+10)/20 to 1 ulp
            float u  = fabsf(xo);
            // analytic bin: g = log2(1 + alpha*u)/log2(1.2); one v_log_f32
            float g  = __log2f(fmaf(ALPHA, u, 1.0f)) * INV_LOG2R;
            int jp = (int)fminf(g, 31.0f);               // floor, x >= 0 side
            int jn = (int)ceilf(fminf(g, 32.0f));        // ceil,  x <  0 side
            int k  = (xo >= 0.0f) ? (32 + jp) : (32 - jn);

            float4 tb = stbl[(d << 6) + k];              // {v1, slope, F_pre, mesh_k}
            float xm  = xs - tb.w;
            bool cov  = (xs >= 0.0f) && (xs < 1.0f);

            float yc = tb.z + xm * fmaf(0.5f * xm, tb.y, tb.x);
            float dl = fmaf(xm, tb.y, tb.x);
            float yy = cov ? yc : xs;
            dd[d]    = cov ? dl : 1.0f;

            yy = fmaf(yy, 20.0f, -10.0f);
            if (yy > 10.0f)  { yy = fmaf(1e-6f, yy - 10.0f, 10.0f);  ld += LOG_BETA; }
            if (yy < -10.0f) { yy = fmaf(1e-6f, yy + 10.0f, -10.0f); ld += LOG_BETA; }
            yd[d] = yy;
        }

        // sum of logs as logs of pairwise products: 4 x v_log_f32
        // (pair product >= (1e-6)^2 = 1e-12 — no fp32 underflow)
        float l01 = __log2f(dd[0] * dd[1]);
        float l23 = __log2f(dd[2] * dd[3]);
        float l45 = __log2f(dd[4] * dd[5]);
        float l67 = __log2f(dd[6] * dd[7]);
        ld = fmaf((l01 + l23) + (l45 + l67), LN2F, ld);

        float4* yo = (float4*)y_out + 2 * (size_t)i;
        yo[0] = make_float4(yd[0], yd[1], yd[2], yd[3]);
        yo[1] = make_float4(yd[4], yd[5], yd[6], yd[7]);
        ld_out[i] = ld;
    };

    // ---- main loop: guard-free 2-deep software pipeline ----
    for (int j = 0; j < iters; ++j) {
        float4 An, Bn; float Ln;
        const bool more = (j + 1 < iters);              // wave-uniform
        if (more) {
            size_t ix = (size_t)i0 + (size_t)(j + 1) * T;
            An = xv[2 * ix];
            Bn = xv[2 * ix + 1];
            Ln = logdet_in[ix];
        }
        __builtin_amdgcn_sched_barrier(0);   // keep prefetch above the compute

        body(Ac, Bc, Lc, i0 + j * T);

        if (more) { Ac = An; Bc = Bn; Lc = Ln; }
    }

    // ---- remainder (never runs when T | n; kept for generality) ----
    int ir = i0 + iters * T;
    if (ir < n) {
        float4 A = xv[2 * (size_t)ir];
        float4 B = xv[2 * (size_t)ir + 1];
        float  L = logdet_in[ir];
        body(A, B, L, ir);
    }
}

extern "C" void kernel_launch(void* const* d_in, const int* in_sizes, int n_in,
                              void* d_out, int out_size, void* d_ws, size_t ws_size,
                              hipStream_t stream) {
    const float* x      = (const float*)d_in[0];   // [N, 8]
    const float* logdet = (const float*)d_in[1];   // [N, 1]
    const float* p      = (const float*)d_in[2];   // [63, 8]

    const int n = in_sizes[1];                     // N points
    float* y_out  = (float*)d_out;                 // [N*8]
    float* ld_out = (float*)d_out + (size_t)n * NDIM;  // [N]

    const int block = 256;
    int grid = 2048;                               // max co-resident (8 blocks/CU)
    if (grid * block > n) grid = (n + block - 1) / block;
    cdfq_fused<<<grid, block, 0, stream>>>(x, logdet, p, y_out, ld_out, n);
}

// Round 5
// 138.859 us; speedup vs baseline: 1.0848x; 1.0055x over previous
//
#include <hip/hip_runtime.h>
#include <hip/hip_bf16.h>
#include <math.h>

// Problem constants (from reference)
#define NDIM   8
#define NBINS  64
#define LOG_BETA   (-13.815510557964274f)  // log(1e-6)
#define LN2F       0.69314718055994531f
// mesh is geometric: boundary_j (original coords) = x1L*(1.2^j-1)/0.2, j=0..32
// bin index from |x|: g = log2(1 + ALPHA*|x|) / log2(1.2);  ALPHA = (1.2^32-1)/10
#define ALPHA      34.0821892f
#define INV_LOG2R  3.80178401692393f       // 1/log2(1.2)

// Two threads per point: lane g handles float4 half (g&1) of point (g>>1).
// All x loads / y stores are dense 16 B/lane (no stride-32B AoS penalty).
__global__ __launch_bounds__(256, 8) void cdfq_fused(const float* __restrict__ x,
                                                     const float* __restrict__ logdet_in,
                                                     const float* __restrict__ p,
                                                     float* __restrict__ y_out,
                                                     float* __restrict__ ld_out,
                                                     int n)
{
    __shared__ float  mesh[65];
    __shared__ float  elmt[64];
    __shared__ float  sc[NDIM];
    __shared__ float  pdfs[NDIM][65];      // [d][k] — bank-friendly (65 stride)
    __shared__ float4 stbl[NDIM * NBINS];  // [d][k]: {v1, slope, F_pre, mesh_k}

    const int t  = threadIdx.x;
    const int T  = gridDim.x * blockDim.x;         // work-item stride
    const int i0 = blockIdx.x * blockDim.x + t;
    const int G  = 2 * n;                          // work items = half-points
    const int iters = G / T;                       // wave-uniform (8 here)
    const float4* xv4 = (const float4*)x;

    // ---- prologue loads for iteration 0: issued BEFORE prep so the first
    //      memory latency hides behind prep's VALU/shuffle work ----
    float4 Xc; float Lc;
    if (iters > 0) {
        Xc = xv4[i0];
        Lc = logdet_in[i0 >> 1];
    }
    __builtin_amdgcn_sched_barrier(0);   // do not sink these below prep

    // ---- prep phase (redundant per block; removes a serializing launch) ----
    if (t < 65) {
        float fidx = (float)t - 32.0f;
        float a = fabsf(fidx);
        float x1L = 2.0f / (powf(1.2f, 32.0f) - 1.0f);
        float xr = x1L * (powf(1.2f, a) - 1.0f) / 0.2f;
        xr = (fidx >= 0.0f) ? xr : -xr;
        xr = (xr + 10.0f) / 20.0f;
        if (t == 0)  xr = 0.0f;
        if (t == 64) xr = 1.0f;
        mesh[t] = xr;
    }
    for (int idx = t; idx < 63 * NDIM; idx += 256) {      // exp(p) -> pdfs[d][k+1]
        int d = idx & 7, k = idx >> 3;
        pdfs[d][k + 1] = expf(p[k * NDIM + d]);
    }
    if (t < NDIM) { pdfs[t][0] = 1e-6f; pdfs[t][64] = 1e-6f; }
    __syncthreads();
    if (t < 64) elmt[t] = mesh[t + 1] - mesh[t];
    __syncthreads();

    if (t < 64) {   // wave 0: per-dim normalization scale via shuffle reduce
        for (int d = 0; d < NDIM; ++d) {
            float w = 0.0f;
            if (t < 63) w = pdfs[d][t + 1] * 0.5f * (elmt[t] + elmt[t + 1]);
            for (int off = 32; off > 0; off >>= 1) w += __shfl_down(w, off);
            if (t == 0) sc[d] = (1.0f - (elmt[0] + elmt[63]) * 5e-7f) / w;
        }
    }
    __syncthreads();
    for (int idx = t; idx < 63 * NDIM; idx += 256) {      // apply scale
        int d = idx & 7, k = idx >> 3;
        pdfs[d][k + 1] *= sc[d];
    }
    __syncthreads();
    if (t < 64) {   // wave 0: cell integral + exclusive scan per dim + pack table
        for (int d = 0; d < NDIM; ++d) {
            float c0 = 0.5f * (pdfs[d][t] + pdfs[d][t + 1]) * elmt[t];
            float v = c0;
            for (int off = 1; off < 64; off <<= 1) {
                float w = __shfl_up(v, off);
                if (t >= off) v += w;
            }
            float Fpre = v - c0;                 // exclusive prefix
            float v1 = pdfs[d][t];
            float v2 = pdfs[d][t + 1];
            stbl[d * 64 + t] = make_float4(v1, (v2 - v1) / elmt[t], Fpre, mesh[t]);
        }
    }
    __syncthreads();

    // ---- per-half-point body: 4 dims, one shfl_xor to combine logdet ----
    auto body = [&](float4 X, float Lin, int g) {
        const int q     = g >> 1;
        const int dbase = (g & 1) << 2;            // dims 0-3 or 4-7
        float xd[4] = {X.x, X.y, X.z, X.w};
        float yd[4], dd[4];
        float extra = 0.0f;

#pragma unroll
        for (int dl = 0; dl < 4; ++dl) {
            float xo = xd[dl];
            float xs = fmaf(xo, 0.05f, 0.5f);            // (x+10)/20 to 1 ulp
            float u  = fabsf(xo);
            // analytic bin: g = log2(1 + alpha*u)/log2(1.2); one v_log_f32
            float gg = __log2f(fmaf(ALPHA, u, 1.0f)) * INV_LOG2R;
            int jp = (int)fminf(gg, 31.0f);              // floor, x >= 0 side
            int jn = (int)ceilf(fminf(gg, 32.0f));       // ceil,  x <  0 side
            int k  = (xo >= 0.0f) ? (32 + jp) : (32 - jn);

            float4 tb = stbl[((dbase + dl) << 6) + k];   // {v1, slope, F_pre, mesh_k}
            float xm  = xs - tb.w;
            bool cov  = (xs >= 0.0f) && (xs < 1.0f);

            float yc = tb.z + xm * fmaf(0.5f * xm, tb.y, tb.x);
            float dv = fmaf(xm, tb.y, tb.x);
            float yy = cov ? yc : xs;
            dd[dl]   = cov ? dv : 1.0f;

            yy = fmaf(yy, 20.0f, -10.0f);
            if (yy > 10.0f)  { yy = fmaf(1e-6f, yy - 10.0f, 10.0f);  extra += LOG_BETA; }
            if (yy < -10.0f) { yy = fmaf(1e-6f, yy + 10.0f, -10.0f); extra += LOG_BETA; }
            yd[dl] = yy;
        }

        // 2 x v_log_f32 of pairwise products (each product >= 1e-12, no underflow)
        float l2 = __log2f(dd[0] * dd[1]) + __log2f(dd[2] * dd[3]);
        float contrib = fmaf(l2, LN2F, extra);
        float cross   = __shfl_xor(contrib, 1);    // partner half-point

        ((float4*)y_out)[g] = make_float4(yd[0], yd[1], yd[2], yd[3]);
        if ((g & 1) == 0) ld_out[q] = Lin + contrib + cross;
    };

    // ---- main loop: guard-free 2-deep software pipeline ----
    for (int j = 0; j < iters; ++j) {
        float4 Xn; float Ln;
        const bool more = (j + 1 < iters);         // wave-uniform
        if (more) {
            int gx = i0 + (j + 1) * T;
            Xn = xv4[gx];
            Ln = logdet_in[gx >> 1];
        }
        __builtin_amdgcn_sched_barrier(0);         // keep prefetch above the compute

        body(Xc, Lc, i0 + j * T);

        if (more) { Xc = Xn; Lc = Ln; }
    }

    // ---- remainder (never runs when T | G; kept for generality) ----
    int gr = i0 + iters * T;
    if (gr < G) {
        body(xv4[gr], logdet_in[gr >> 1], gr);     // pairs never split: G is even,
                                                   // partner is adjacent lane
    }
}

extern "C" void kernel_launch(void* const* d_in, const int* in_sizes, int n_in,
                              void* d_out, int out_size, void* d_ws, size_t ws_size,
                              hipStream_t stream) {
    const float* x      = (const float*)d_in[0];   // [N, 8]
    const float* logdet = (const float*)d_in[1];   // [N, 1]
    const float* p      = (const float*)d_in[2];   // [63, 8]

    const int n = in_sizes[1];                     // N points
    float* y_out  = (float*)d_out;                 // [N*8]
    float* ld_out = (float*)d_out + (size_t)n * NDIM;  // [N]

    const int block = 256;
    int grid = 2048;                               // 8 blocks/CU co-resident
    if ((long long)grid * block > 2LL * n) grid = (2 * n + block - 1) / block;
    cdfq_fused<<<grid, block, 0, stream>>>(x, logdet, p, y_out, ld_out, n);
}